// Round 6
// baseline (343.670 us; speedup 1.0000x reference)
//
#include <hip/hip_runtime.h>

// ---------------------------------------------------------------------------
// GCN 2-layer: h1 = relu(LN(Ahat @ (x W1) + b1)); out = Ahat @ (h1 W2) + b2
// Ahat = D^-1/2 (A+I) D^-1/2, CSR built on-device each call (no feature atomics)
// Round 1: single-block scan (133us, 1 CU) -> hierarchical scan.
// Round 2: gemm_rt (70us, 220MB fetch) -> LDS-tiled gemm_lds.
// Round 3: prop kernels latency-serial -> pipelined gathers; h0 -> bf16.
// Round 4: fill_k 8x write amplification -> 4B payload + rank-in-count.
// Round 5: prop gathers miss L2 (12.8MB table > 4MB/XCD) -> shard features
//          across XCDs: tables stored fc-major [8][n][chunk], prop blocks pick
//          fc = blockIdx.x & 7 (round-robin XCD mapping) so each XCD gathers
//          from a 1.6MB/0.8MB L2-resident slice. LN split into its own
//          streaming kernel (prop can no longer see the full row).
// ---------------------------------------------------------------------------

__device__ __forceinline__ unsigned short f2bf(float f) {
    unsigned u = __float_as_uint(f);
    u += 0x7FFF + ((u >> 16) & 1);     // round-to-nearest-even
    return (unsigned short)(u >> 16);
}
__device__ __forceinline__ float bfLo(unsigned g) { return __uint_as_float(g << 16); }
__device__ __forceinline__ float bfHi(unsigned g) { return __uint_as_float(g & 0xFFFF0000u); }

// count + rank in one pass: rank = arrival order within dst bucket.
__global__ void count_k(const int* __restrict__ dst, int* __restrict__ cnt,
                        int* __restrict__ rank, int e) {
    int i = blockIdx.x * blockDim.x + threadIdx.x;
    if (i < e) rank[i] = atomicAdd(&cnt[dst[i]], 1);
}

// Pass 1: per-block inclusive scan of cnt -> incl, block totals -> bsum.
__global__ __launch_bounds__(1024) void scan1_k(const int* __restrict__ cnt,
                                                int* __restrict__ incl,
                                                int* __restrict__ bsum, int n) {
    __shared__ int lds[1024];
    int t = threadIdx.x;
    int i = blockIdx.x * 1024 + t;
    int v = (i < n) ? cnt[i] : 0;
    lds[t] = v;
    __syncthreads();
#pragma unroll
    for (int d = 1; d < 1024; d <<= 1) {
        int u = (t >= d) ? lds[t - d] : 0;
        __syncthreads();
        lds[t] += u;
        __syncthreads();
    }
    if (i < n) incl[i] = lds[t];
    if (t == 1023) bsum[blockIdx.x] = lds[1023];
}

// Pass 2: exclusive scan of the block sums (single wave).
__global__ __launch_bounds__(64) void scan2_k(const int* __restrict__ bsum,
                                              int* __restrict__ bpre, int nb) {
    int t = threadIdx.x;
    int v = (t < nb) ? bsum[t] : 0;
#pragma unroll
    for (int d = 1; d < 64; d <<= 1) {
        int u = __shfl_up(v, d);
        if (t >= d) v += u;
    }
    if (t < nb) bpre[t] = v - bsum[t];   // exclusive
}

// Pass 3: offs (exclusive prefix), dinv, sentinel offs[n].
__global__ __launch_bounds__(1024) void scan3_k(const int* __restrict__ cnt,
                                                const int* __restrict__ incl,
                                                const int* __restrict__ bpre,
                                                int* __restrict__ offs,
                                                float* __restrict__ dinv, int n) {
    int i = blockIdx.x * 1024 + threadIdx.x;
    if (i >= n) return;
    int c = cnt[i];
    int inc = incl[i] + bpre[blockIdx.x];
    offs[i] = inc - c;
    dinv[i] = rsqrtf((float)(c + 1));    // deg includes self loop
    if (i == n - 1) offs[n] = inc;
}

// Scatter src ids into CSR slots. 4B payload, no atomics; 3.2MB target fits
// per-XCD L2 so partial lines coalesce before writeback.
__global__ void fill_k(const int* __restrict__ src, const int* __restrict__ dst,
                       const int* __restrict__ rank, const int* __restrict__ offs,
                       int* __restrict__ esrc, int e) {
    int i = blockIdx.x * blockDim.x + threadIdx.x;
    if (i >= e) return;
    esrc[offs[dst[i]] + rank[i]] = src[i];
}

// LDS-tiled GEMM: X[n,128] @ W[128,M] -> packed-bf16 H in fc-major layout
// tab[fc][node][CH] (CH uints of 2 features each; 8 fc chunks). Block = 64
// rows, 4 waves; wave w owns cols [w*M/4,(w+1)*M/4). W reads -> s_load.
template<int M>
__global__ __launch_bounds__(256) void gemm_lds(const float* __restrict__ X,
                                                const float* __restrict__ W,
                                                unsigned* __restrict__ tab, int n) {
    __shared__ float Xs[64][129];
    int r0 = blockIdx.x * 64;
    int t = threadIdx.x;
    int rows = min(64, n - r0);
    const float4* X4 = (const float4*)(X + (size_t)r0 * 128);
#pragma unroll
    for (int i = 0; i < 8; ++i) {
        int u = t + i * 256;          // float4 index within stripe
        int row = u >> 5;             // 32 float4 per row
        if (row < rows) {
            float4 v = X4[u];
            int col = (u & 31) << 2;
            Xs[row][col]     = v.x;
            Xs[row][col + 1] = v.y;
            Xs[row][col + 2] = v.z;
            Xs[row][col + 3] = v.w;
        }
    }
    __syncthreads();

    constexpr int CW = M / 4;         // cols per wave (32 or 16)
    constexpr int CH = M / 16;        // uints per fc chunk (8 or 4)
    int wv = __builtin_amdgcn_readfirstlane(t >> 6);
    int lane = t & 63;
    int c0 = wv * CW;
    if (lane >= rows) return;

    float acc[CW];
#pragma unroll
    for (int j = 0; j < CW; ++j) acc[j] = 0.f;

    for (int k = 0; k < 128; k += 4) {
        float x0 = Xs[lane][k];
        float x1 = Xs[lane][k + 1];
        float x2 = Xs[lane][k + 2];
        float x3 = Xs[lane][k + 3];
        const float* Wk = &W[(size_t)k * M + c0];
#pragma unroll
        for (int j = 0; j < CW; ++j) {
            float a = acc[j];
            a = fmaf(x0, Wk[j], a);
            a = fmaf(x1, Wk[M + j], a);
            a = fmaf(x2, Wk[2 * M + j], a);
            a = fmaf(x3, Wk[3 * M + j], a);
            acc[j] = a;
        }
    }

    unsigned pk[CW / 2];
#pragma unroll
    for (int j = 0; j < CW / 2; ++j)
        pk[j] = (unsigned)f2bf(acc[2 * j]) | ((unsigned)f2bf(acc[2 * j + 1]) << 16);
    // wave's CW/2 uints span exactly 2 fc chunks of CH uints each
#pragma unroll
    for (int h = 0; h < (CW / 2) / CH; ++h) {
        int fc = (c0 / 2) / CH + h;
        unsigned* dstp = tab + (size_t)fc * n * CH + (size_t)(r0 + lane) * CH;
#pragma unroll
        for (int q = 0; q < CH; q += 4)
            *(uint4*)&dstp[q] = make_uint4(pk[h * CH + q], pk[h * CH + q + 1],
                                           pk[h * CH + q + 2], pk[h * CH + q + 3]);
    }
}

// Layer-1 gather, XCD-sharded: block handles (node group, fc=bid&7); wave per
// node; lanes = 8 edge-slots x 8 uint-chunks. Gathers hit only this fc's
// 1.6MB slice -> L2-resident. Writes pre-LN f32 partials to h1[node][128].
__global__ __launch_bounds__(256) void prop_g1(const unsigned* __restrict__ tab,
                                               const int* __restrict__ offs,
                                               const int* __restrict__ esrc,
                                               const float* __restrict__ dinv,
                                               float* __restrict__ h1, int n) {
    int bid = blockIdx.x;
    int fc = __builtin_amdgcn_readfirstlane(bid & 7);
    int node = __builtin_amdgcn_readfirstlane((bid >> 3) * 4 + (threadIdx.x >> 6));
    if (node >= n) return;
    int lane = threadIdx.x & 63;
    int es = lane >> 3, u = lane & 7;
    const unsigned* t = tab + (size_t)fc * n * 8;
    float di = dinv[node];
    float a0 = 0.f, a1 = 0.f;
    if (es == 0) {
        unsigned self = t[node * 8 + u];
        a0 = bfLo(self) * di * di;
        a1 = bfHi(self) * di * di;
    }
    int s0 = offs[node], s1 = offs[node + 1];
    if (s0 < s1) {
        int k = s0;
        int idx = k + es;
        bool v = idx < s1;
        int src = esrc[v ? idx : s1 - 1];
        float w0 = v ? dinv[src] * di : 0.f;
        unsigned g0 = t[src * 8 + u];
        for (k += 8; k < s1; k += 8) {
            idx = k + es;
            v = idx < s1;
            int src1 = esrc[v ? idx : s1 - 1];
            float w1 = v ? dinv[src1] * di : 0.f;
            unsigned g1 = t[src1 * 8 + u];
            a0 = fmaf(bfLo(g0), w0, a0);
            a1 = fmaf(bfHi(g0), w0, a1);
            g0 = g1; w0 = w1;
        }
        a0 = fmaf(bfLo(g0), w0, a0);
        a1 = fmaf(bfHi(g0), w0, a1);
    }
#pragma unroll
    for (int off = 8; off < 64; off <<= 1) {
        a0 += __shfl_xor(a0, off);
        a1 += __shfl_xor(a1, off);
    }
    if (es == 0)
        ((float2*)h1)[(size_t)node * 64 + fc * 8 + u] = make_float2(a0, a1);
}

// Bias + LayerNorm + ReLU over h1[n][128], in place. Wave per node.
__global__ __launch_bounds__(256) void ln_k(float* __restrict__ h1,
                                            const float* __restrict__ b1,
                                            const float* __restrict__ gamma,
                                            const float* __restrict__ beta, int n) {
    int wid = __builtin_amdgcn_readfirstlane((blockIdx.x * blockDim.x + threadIdx.x) >> 6);
    int lane = threadIdx.x & 63;
    if (wid >= n) return;
    float2 v = ((float2*)h1)[(size_t)wid * 64 + lane];
    float a0 = v.x + b1[2 * lane];
    float a1 = v.y + b1[2 * lane + 1];
    float sum = a0 + a1, sq = a0 * a0 + a1 * a1;
#pragma unroll
    for (int off = 32; off > 0; off >>= 1) {
        sum += __shfl_xor(sum, off);
        sq  += __shfl_xor(sq, off);
    }
    float mu  = sum * (1.f / 128.f);
    float var = fmaxf(sq * (1.f / 128.f) - mu * mu, 0.f);
    float rstd = rsqrtf(var + 1e-6f);
    float y0 = fmaxf((a0 - mu) * rstd * gamma[2 * lane] + beta[2 * lane], 0.f);
    float y1 = fmaxf((a1 - mu) * rstd * gamma[2 * lane + 1] + beta[2 * lane + 1], 0.f);
    ((float2*)h1)[(size_t)wid * 64 + lane] = make_float2(y0, y1);
}

// Layer-2 gather, XCD-sharded (0.8MB slice/XCD): lanes = 16 edge-slots x
// 4 uint-chunks. Writes final out (+bias) directly.
__global__ __launch_bounds__(256) void prop_o2(const unsigned* __restrict__ tab,
                                               const int* __restrict__ offs,
                                               const int* __restrict__ esrc,
                                               const float* __restrict__ dinv,
                                               const float* __restrict__ b2,
                                               float* __restrict__ out, int n) {
    int bid = blockIdx.x;
    int fc = __builtin_amdgcn_readfirstlane(bid & 7);
    int node = __builtin_amdgcn_readfirstlane((bid >> 3) * 4 + (threadIdx.x >> 6));
    if (node >= n) return;
    int lane = threadIdx.x & 63;
    int es = lane >> 2, u = lane & 3;
    const unsigned* t = tab + (size_t)fc * n * 4;
    float di = dinv[node];
    float a0 = 0.f, a1 = 0.f;
    if (es == 0) {
        unsigned self = t[node * 4 + u];
        a0 = bfLo(self) * di * di;
        a1 = bfHi(self) * di * di;
    }
    int s0 = offs[node], s1 = offs[node + 1];
    if (s0 < s1) {
        int k = s0;
        int idx = k + es;
        bool v = idx < s1;
        int src = esrc[v ? idx : s1 - 1];
        float w0 = v ? dinv[src] * di : 0.f;
        unsigned g0 = t[src * 4 + u];
        for (k += 16; k < s1; k += 16) {
            idx = k + es;
            v = idx < s1;
            int src1 = esrc[v ? idx : s1 - 1];
            float w1 = v ? dinv[src1] * di : 0.f;
            unsigned g1 = t[src1 * 4 + u];
            a0 = fmaf(bfLo(g0), w0, a0);
            a1 = fmaf(bfHi(g0), w0, a1);
            g0 = g1; w0 = w1;
        }
        a0 = fmaf(bfLo(g0), w0, a0);
        a1 = fmaf(bfHi(g0), w0, a1);
    }
#pragma unroll
    for (int off = 4; off < 64; off <<= 1) {
        a0 += __shfl_xor(a0, off);
        a1 += __shfl_xor(a1, off);
    }
    if (es == 0) {
        float2 o = make_float2(a0 + b2[fc * 8 + 2 * u], a1 + b2[fc * 8 + 2 * u + 1]);
        ((float2*)out)[(size_t)node * 32 + fc * 4 + u] = o;
    }
}

extern "C" void kernel_launch(void* const* d_in, const int* in_sizes, int n_in,
                              void* d_out, int out_size, void* d_ws, size_t ws_size,
                              hipStream_t stream) {
    const float* x     = (const float*)d_in[0];
    const int*   ei    = (const int*)d_in[1];
    const float* W1    = (const float*)d_in[2];
    const float* b1    = (const float*)d_in[3];
    const float* gam   = (const float*)d_in[4];
    const float* bet   = (const float*)d_in[5];
    const float* W2    = (const float*)d_in[6];
    const float* b2    = (const float*)d_in[7];
    float* out = (float*)d_out;

    int n = in_sizes[0] / 128;   // 50000
    int e = in_sizes[1] / 2;     // 800000
    const int* src = ei;
    const int* dst = ei + e;

    char* p = (char*)d_ws;
    auto alloc = [&](size_t bytes) {
        void* q = (void*)p;
        p += (bytes + 255) & ~(size_t)255;
        return q;
    };
    int*      cnt  = (int*)alloc((size_t)n * 4);
    int*      offs = (int*)alloc((size_t)(n + 1) * 4);
    int*      rank = (int*)alloc((size_t)e * 4);
    float*    dinv = (float*)alloc((size_t)n * 4);
    int*      esrc = (int*)alloc((size_t)e * 4);
    unsigned* h0b  = (unsigned*)alloc((size_t)n * 64 * 4);  // bf16 fc-major [8][n][8] (12.8MB)
    float*    h1   = (float*)alloc((size_t)n * 128 * 4);    // pre-LN f32 [n][128]

    // Layer-2 bf16 table [8][n][4] aliases h0b (dead after prop_g1).
    unsigned* h2b = h0b;
    // Scan scratch also aliases h0b (dead before gemm1 writes it).
    int* incl = (int*)h0b;
    int* bsum = incl + n;
    int* bpre = bsum + 64;

    int nb = (n + 1023) / 1024;  // 49 blocks for n=50000

    hipMemsetAsync(cnt, 0, (size_t)n * 4, stream);
    count_k<<<(e + 255) / 256, 256, 0, stream>>>(dst, cnt, rank, e);
    scan1_k<<<nb, 1024, 0, stream>>>(cnt, incl, bsum, n);
    scan2_k<<<1, 64, 0, stream>>>(bsum, bpre, nb);
    scan3_k<<<nb, 1024, 0, stream>>>(cnt, incl, bpre, offs, dinv, n);
    fill_k<<<(e + 255) / 256, 256, 0, stream>>>(src, dst, rank, offs, esrc, e);

    int gb = (n + 63) / 64;        // 782 blocks
    int pb = ((n + 3) / 4) * 8;    // (node groups) x 8 fc = 100000 blocks
    gemm_lds<128><<<gb, 256, 0, stream>>>(x, W1, h0b, n);
    prop_g1<<<pb, 256, 0, stream>>>(h0b, offs, esrc, dinv, h1, n);
    ln_k<<<(n + 3) / 4, 256, 0, stream>>>(h1, b1, gam, bet, n);
    gemm_lds<64><<<gb, 256, 0, stream>>>(h1, W2, h2b, n);
    prop_o2<<<pb, 256, 0, stream>>>(h2b, offs, esrc, dinv, b2, out, n);
}

// Round 8
// 207.947 us; speedup vs baseline: 1.6527x; 1.6527x over previous
//
#include <hip/hip_runtime.h>

// ---------------------------------------------------------------------------
// GCN 2-layer: h1 = relu(LN(Ahat @ (x W1) + b1)); out = Ahat @ (h1 W2) + b2
// Ahat = D^-1/2 (A+I) D^-1/2, CSR built on-device each call (no feature atomics)
// Round 1: single-block scan (133us, 1 CU) -> hierarchical scan.
// Round 2: gemm_rt (70us, 220MB fetch) -> LDS-tiled gemm_lds.
// Round 3: prop kernels latency-serial -> pipelined gathers; h0 -> bf16.
// Round 4: fill_k 8x write amplification -> 4B payload + rank-in-count.
// Round 5: XCD feature-sharding: FETCH 87->21MB (L2-residency confirmed) but
//          dur 53->111us -- longer per-edge dependent chain + 8x descriptor
//          replication. REVERTED.
// Round 6: round-4 structure + packed (src<<16 | bf16(w)) edge payload (kills
//          per-edge dinv gather; src<2^16, w>0 so bf16 fits 16 bits),
//          NT loads/stores on one-touch streams (protect gather tables in L2),
//          prop_out does 2 edges per wave-instruction.
// Round 7: compile fix — NT store needs a clang ext_vector type, not HIP float2.
// ---------------------------------------------------------------------------

typedef float f32x2 __attribute__((ext_vector_type(2)));

__device__ __forceinline__ unsigned short f2bf(float f) {
    unsigned u = __float_as_uint(f);
    u += 0x7FFF + ((u >> 16) & 1);     // round-to-nearest-even
    return (unsigned short)(u >> 16);
}
__device__ __forceinline__ float bfLo(unsigned g) { return __uint_as_float(g << 16); }
__device__ __forceinline__ float bfHi(unsigned g) { return __uint_as_float(g & 0xFFFF0000u); }

// count + rank in one pass: rank = arrival order within dst bucket.
__global__ void count_k(const int* __restrict__ dst, int* __restrict__ cnt,
                        int* __restrict__ rank, int e) {
    int i = blockIdx.x * blockDim.x + threadIdx.x;
    if (i < e) {
        int r = atomicAdd(&cnt[dst[i]], 1);
        __builtin_nontemporal_store(r, &rank[i]);
    }
}

// Pass 1: per-block inclusive scan of cnt -> incl, block totals -> bsum.
__global__ __launch_bounds__(1024) void scan1_k(const int* __restrict__ cnt,
                                                int* __restrict__ incl,
                                                int* __restrict__ bsum, int n) {
    __shared__ int lds[1024];
    int t = threadIdx.x;
    int i = blockIdx.x * 1024 + t;
    int v = (i < n) ? cnt[i] : 0;
    lds[t] = v;
    __syncthreads();
#pragma unroll
    for (int d = 1; d < 1024; d <<= 1) {
        int u = (t >= d) ? lds[t - d] : 0;
        __syncthreads();
        lds[t] += u;
        __syncthreads();
    }
    if (i < n) incl[i] = lds[t];
    if (t == 1023) bsum[blockIdx.x] = lds[1023];
}

// Pass 2: exclusive scan of the block sums (single wave).
__global__ __launch_bounds__(64) void scan2_k(const int* __restrict__ bsum,
                                              int* __restrict__ bpre, int nb) {
    int t = threadIdx.x;
    int v = (t < nb) ? bsum[t] : 0;
#pragma unroll
    for (int d = 1; d < 64; d <<= 1) {
        int u = __shfl_up(v, d);
        if (t >= d) v += u;
    }
    if (t < nb) bpre[t] = v - bsum[t];   // exclusive
}

// Pass 3: offs (exclusive prefix), dinv, sentinel offs[n].
__global__ __launch_bounds__(1024) void scan3_k(const int* __restrict__ cnt,
                                                const int* __restrict__ incl,
                                                const int* __restrict__ bpre,
                                                int* __restrict__ offs,
                                                float* __restrict__ dinv, int n) {
    int i = blockIdx.x * 1024 + threadIdx.x;
    if (i >= n) return;
    int c = cnt[i];
    int inc = incl[i] + bpre[blockIdx.x];
    offs[i] = inc - c;
    dinv[i] = rsqrtf((float)(c + 1));    // deg includes self loop
    if (i == n - 1) offs[n] = inc;
}

// Scatter packed (src<<16 | bf16(w)) into CSR slots. 4B payload, no atomics;
// 3.2MB target fits per-XCD L2 so partial lines coalesce before writeback.
__global__ void fill_k(const int* __restrict__ src, const int* __restrict__ dst,
                       const int* __restrict__ rank, const int* __restrict__ offs,
                       const float* __restrict__ dinv,
                       unsigned* __restrict__ epk, int e) {
    int i = blockIdx.x * blockDim.x + threadIdx.x;
    if (i >= e) return;
    int s = src[i], d = dst[i];
    float w = dinv[s] * dinv[d];         // in (0,1], sign bit 0 -> bf16 fits 16b
    epk[offs[d] + rank[i]] = ((unsigned)s << 16) | (unsigned)f2bf(w);
}

// LDS-tiled GEMM: X[n,128] @ W[128,M] -> H[n,M]. Block = 64 rows, 4 waves;
// wave w owns cols [w*M/4,(w+1)*M/4). W reads wave-uniform -> s_load.
// BF16 epilogue packs col pairs {2j,2j+1} into one uint (lo,hi).
template<int M>
__global__ __launch_bounds__(256) void gemm_lds(const float* __restrict__ X,
                                                const float* __restrict__ W,
                                                unsigned* __restrict__ Hb, int n) {
    __shared__ float Xs[64][129];
    int r0 = blockIdx.x * 64;
    int t = threadIdx.x;
    int rows = min(64, n - r0);
    const float4* X4 = (const float4*)(X + (size_t)r0 * 128);
#pragma unroll
    for (int i = 0; i < 8; ++i) {
        int u = t + i * 256;          // float4 index within stripe
        int row = u >> 5;             // 32 float4 per row
        if (row < rows) {
            float4 v = X4[u];
            int col = (u & 31) << 2;
            Xs[row][col]     = v.x;
            Xs[row][col + 1] = v.y;
            Xs[row][col + 2] = v.z;
            Xs[row][col + 3] = v.w;
        }
    }
    __syncthreads();

    constexpr int CW = M / 4;         // cols per wave (32 or 16)
    int wv = __builtin_amdgcn_readfirstlane(t >> 6);
    int lane = t & 63;
    int c0 = wv * CW;
    if (lane >= rows) return;

    float acc[CW];
#pragma unroll
    for (int j = 0; j < CW; ++j) acc[j] = 0.f;

    for (int k = 0; k < 128; k += 4) {
        float x0 = Xs[lane][k];
        float x1 = Xs[lane][k + 1];
        float x2 = Xs[lane][k + 2];
        float x3 = Xs[lane][k + 3];
        const float* Wk = &W[(size_t)k * M + c0];
#pragma unroll
        for (int j = 0; j < CW; ++j) {
            float a = acc[j];
            a = fmaf(x0, Wk[j], a);
            a = fmaf(x1, Wk[M + j], a);
            a = fmaf(x2, Wk[2 * M + j], a);
            a = fmaf(x3, Wk[3 * M + j], a);
            acc[j] = a;
        }
    }

    unsigned pk[CW / 2];
#pragma unroll
    for (int j = 0; j < CW / 2; ++j)
        pk[j] = (unsigned)f2bf(acc[2 * j]) | ((unsigned)f2bf(acc[2 * j + 1]) << 16);
    unsigned* Hp = Hb + (size_t)(r0 + lane) * (M / 2) + c0 / 2;
#pragma unroll
    for (int j = 0; j < CW / 2; j += 4)
        *(uint4*)&Hp[j] = make_uint4(pk[j], pk[j + 1], pk[j + 2], pk[j + 3]);
}

// Layer 1 propagation + bias + LayerNorm + ReLU. One wave per node, lane
// holds features {2*lane, 2*lane+1}. 8-deep gather pipeline; edge weight
// unpacked from the payload (no per-edge dinv gather).
__global__ __launch_bounds__(256) void prop_ln(const unsigned* __restrict__ h0b,
                                               const int* __restrict__ offs,
                                               const unsigned* __restrict__ epk,
                                               const float* __restrict__ dinv,
                                               const float* __restrict__ b1,
                                               const float* __restrict__ gamma,
                                               const float* __restrict__ beta,
                                               float* __restrict__ h1, int n) {
    int wid = __builtin_amdgcn_readfirstlane((blockIdx.x * blockDim.x + threadIdx.x) >> 6);
    int lane = threadIdx.x & 63;
    if (wid >= n) return;
    float di = dinv[wid];
    unsigned self = h0b[(size_t)wid * 64 + lane];
    float a0 = bfLo(self) * di * di;   // self loop, norm = dinv^2
    float a1 = bfHi(self) * di * di;

    int s0 = offs[wid], s1 = offs[wid + 1];
    if (s0 < s1) {
        int k = s0;
        int sj[8]; float wj[8];
#pragma unroll
        for (int j = 0; j < 8; ++j) {
            int idx = k + j;
            unsigned p = __builtin_nontemporal_load(&epk[min(idx, s1 - 1)]);
            sj[j] = (int)(p >> 16);
            wj[j] = (idx < s1) ? bfLo(p) : 0.f;
        }
        while (k < s1) {
            unsigned g[8];
#pragma unroll
            for (int j = 0; j < 8; ++j) g[j] = h0b[(size_t)sj[j] * 64 + lane];
            k += 8;
            int s2[8]; float w2[8];
#pragma unroll
            for (int j = 0; j < 8; ++j) {
                int idx = k + j;
                unsigned p = __builtin_nontemporal_load(&epk[min(max(idx, s0), s1 - 1)]);
                s2[j] = (int)(p >> 16);
                w2[j] = (idx < s1) ? bfLo(p) : 0.f;
            }
#pragma unroll
            for (int j = 0; j < 8; ++j) {
                a0 = fmaf(bfLo(g[j]), wj[j], a0);
                a1 = fmaf(bfHi(g[j]), wj[j], a1);
            }
#pragma unroll
            for (int j = 0; j < 8; ++j) { sj[j] = s2[j]; wj[j] = w2[j]; }
        }
    }

    a0 += b1[2 * lane];
    a1 += b1[2 * lane + 1];
    // LayerNorm over 128 features spread across the 64-lane wave
    float sum = a0 + a1, sq = a0 * a0 + a1 * a1;
#pragma unroll
    for (int off = 32; off > 0; off >>= 1) {
        sum += __shfl_xor(sum, off);
        sq  += __shfl_xor(sq, off);
    }
    float mu  = sum * (1.f / 128.f);
    float var = fmaxf(sq * (1.f / 128.f) - mu * mu, 0.f);
    float rstd = rsqrtf(var + 1e-6f);
    float y0 = fmaxf((a0 - mu) * rstd * gamma[2 * lane] + beta[2 * lane], 0.f);
    float y1 = fmaxf((a1 - mu) * rstd * gamma[2 * lane + 1] + beta[2 * lane + 1], 0.f);
    f32x2 y; y.x = y0; y.y = y1;
    __builtin_nontemporal_store(y, &((f32x2*)h1)[(size_t)wid * 64 + lane]);
}

// Layer 2 propagation + bias. One wave per node; 2 edges per instruction:
// lane = (es = lane>>5: edge-in-pair) x (u = lane&31: uint chunk of the
// 64-feature bf16 row). 8-deep pipeline = 16 edges in flight. Final
// cross-half reduce via one shfl_xor(32).
__global__ __launch_bounds__(256) void prop_out(const unsigned* __restrict__ h2b,
                                                const int* __restrict__ offs,
                                                const unsigned* __restrict__ epk,
                                                const float* __restrict__ dinv,
                                                const float* __restrict__ b2,
                                                float* __restrict__ out, int n) {
    int wid = __builtin_amdgcn_readfirstlane((blockIdx.x * blockDim.x + threadIdx.x) >> 6);
    int lane = threadIdx.x & 63;
    if (wid >= n) return;
    int es = lane >> 5, u = lane & 31;
    float di = dinv[wid];
    float a0 = 0.f, a1 = 0.f;
    if (es == 0) {
        unsigned self = h2b[(size_t)wid * 32 + u];
        a0 = bfLo(self) * di * di;
        a1 = bfHi(self) * di * di;
    }

    int s0 = offs[wid], s1 = offs[wid + 1];
    if (s0 < s1) {
        int k = s0;
        int sj[8]; float wj[8];
#pragma unroll
        for (int j = 0; j < 8; ++j) {
            int idx = k + 2 * j + es;
            unsigned p = __builtin_nontemporal_load(&epk[min(idx, s1 - 1)]);
            sj[j] = (int)(p >> 16);
            wj[j] = (idx < s1) ? bfLo(p) : 0.f;
        }
        while (k < s1) {
            unsigned g[8];
#pragma unroll
            for (int j = 0; j < 8; ++j) g[j] = h2b[(size_t)sj[j] * 32 + u];
            k += 16;
            int s2[8]; float w2[8];
#pragma unroll
            for (int j = 0; j < 8; ++j) {
                int idx = k + 2 * j + es;
                unsigned p = __builtin_nontemporal_load(&epk[min(max(idx, s0), s1 - 1)]);
                s2[j] = (int)(p >> 16);
                w2[j] = (idx < s1) ? bfLo(p) : 0.f;
            }
#pragma unroll
            for (int j = 0; j < 8; ++j) {
                a0 = fmaf(bfLo(g[j]), wj[j], a0);
                a1 = fmaf(bfHi(g[j]), wj[j], a1);
            }
#pragma unroll
            for (int j = 0; j < 8; ++j) { sj[j] = s2[j]; wj[j] = w2[j]; }
        }
    }

    a0 += __shfl_xor(a0, 32);
    a1 += __shfl_xor(a1, 32);
    if (es == 0) {
        f32x2 o; o.x = a0 + b2[2 * u]; o.y = a1 + b2[2 * u + 1];
        __builtin_nontemporal_store(o, &((f32x2*)out)[(size_t)wid * 32 + u]);
    }
}

extern "C" void kernel_launch(void* const* d_in, const int* in_sizes, int n_in,
                              void* d_out, int out_size, void* d_ws, size_t ws_size,
                              hipStream_t stream) {
    const float* x     = (const float*)d_in[0];
    const int*   ei    = (const int*)d_in[1];
    const float* W1    = (const float*)d_in[2];
    const float* b1    = (const float*)d_in[3];
    const float* gam   = (const float*)d_in[4];
    const float* bet   = (const float*)d_in[5];
    const float* W2    = (const float*)d_in[6];
    const float* b2    = (const float*)d_in[7];
    float* out = (float*)d_out;

    int n = in_sizes[0] / 128;   // 50000  (must stay < 65536 for packed src)
    int e = in_sizes[1] / 2;     // 800000
    const int* src = ei;
    const int* dst = ei + e;

    char* p = (char*)d_ws;
    auto alloc = [&](size_t bytes) {
        void* q = (void*)p;
        p += (bytes + 255) & ~(size_t)255;
        return q;
    };
    int*      cnt  = (int*)alloc((size_t)n * 4);
    int*      offs = (int*)alloc((size_t)(n + 1) * 4);
    int*      rank = (int*)alloc((size_t)e * 4);
    float*    dinv = (float*)alloc((size_t)n * 4);
    unsigned* epk  = (unsigned*)alloc((size_t)e * 4);
    unsigned* h0b  = (unsigned*)alloc((size_t)n * 64 * 4);  // bf16 [n][64] (12.8MB)
    float*    h1   = (float*)alloc((size_t)n * 128 * 4);    // post-LN f32 [n][128]

    // Layer-2 bf16 table [n][32] aliases h0b (dead after prop_ln).
    unsigned* h2b = h0b;
    // Scan scratch also aliases h0b (dead before gemm1 writes it).
    int* incl = (int*)h0b;
    int* bsum = incl + n;
    int* bpre = bsum + 64;

    int nb = (n + 1023) / 1024;  // 49 blocks for n=50000

    (void)hipMemsetAsync(cnt, 0, (size_t)n * 4, stream);
    count_k<<<(e + 255) / 256, 256, 0, stream>>>(dst, cnt, rank, e);
    scan1_k<<<nb, 1024, 0, stream>>>(cnt, incl, bsum, n);
    scan2_k<<<1, 64, 0, stream>>>(bsum, bpre, nb);
    scan3_k<<<nb, 1024, 0, stream>>>(cnt, incl, bpre, offs, dinv, n);
    fill_k<<<(e + 255) / 256, 256, 0, stream>>>(src, dst, rank, offs, dinv, epk, e);

    int gb = (n + 63) / 64;      // 782 blocks
    gemm_lds<128><<<gb, 256, 0, stream>>>(x, W1, h0b, n);
    prop_ln<<<(n + 3) / 4, 256, 0, stream>>>(h0b, offs, epk, dinv, b1, gam, bet, h1, n);
    gemm_lds<64><<<gb, 256, 0, stream>>>(h1, W2, h2b, n);
    prop_out<<<(n + 3) / 4, 256, 0, stream>>>(h2b, offs, epk, dinv, b2, out, n);
}

// Round 9
// 183.910 us; speedup vs baseline: 1.8687x; 1.1307x over previous
//
#include <hip/hip_runtime.h>

// ---------------------------------------------------------------------------
// GCN 2-layer: h1 = relu(LN(Ahat @ (x W1) + b1)); out = Ahat @ (h1 W2) + b2
// Ahat = D^-1/2 (A+I) D^-1/2, CSR built on-device each call (no feature atomics)
// Round 1: single-block scan (133us, 1 CU) -> hierarchical scan.
// Round 2: gemm_rt (70us, 220MB fetch) -> LDS-tiled gemm_lds.
// Round 3: prop kernels latency-serial -> pipelined gathers; h0 -> bf16.
// Round 4: fill_k 8x write amplification -> 4B payload + rank-in-count.
// Round 5: XCD feature-sharding: L2-resident confirmed but latency-chain x2.
//          REVERTED.
// Round 6/7: packed (src<<16|bf16(w)) edge payload, NT loads/stores.
// Round 8: gemm_lds was s_load/lgkmcnt-drain bound (VALUBusy 21%, 5x off the
//          FMA floor) -> bf16 MFMA gemm: x/W converted to bf16 (W transposed
//          so B-frags are k-contiguous), A-tile LDS XOR-swizzled (T2), K=128
//          unrolled, one barrier; prop_ln writes h1 as packed bf16.
// ---------------------------------------------------------------------------

typedef float f32x2 __attribute__((ext_vector_type(2)));
typedef float f32x4 __attribute__((ext_vector_type(4)));
typedef __bf16 bf16x8 __attribute__((ext_vector_type(8)));

__device__ __forceinline__ unsigned short f2bf(float f) {
    unsigned u = __float_as_uint(f);
    u += 0x7FFF + ((u >> 16) & 1);     // round-to-nearest-even
    return (unsigned short)(u >> 16);
}
__device__ __forceinline__ float bfLo(unsigned g) { return __uint_as_float(g << 16); }
__device__ __forceinline__ float bfHi(unsigned g) { return __uint_as_float(g & 0xFFFF0000u); }

// W1t[c][k] = W1[k][c], W2t[c][k] = W2[k][c] (bf16); also zero cnt.
__global__ __launch_bounds__(256) void cvt_wi(const float* __restrict__ W1,
                                              const float* __restrict__ W2,
                                              unsigned short* __restrict__ W1t,
                                              unsigned short* __restrict__ W2t,
                                              int* __restrict__ cnt, int n) {
    int id = blockIdx.x * 256 + threadIdx.x;
    if (id < 128 * 128) {
        int c = id >> 7, k = id & 127;
        W1t[id] = f2bf(W1[k * 128 + c]);
    } else if (id < 128 * 128 + 64 * 128) {
        int j = id - 128 * 128;
        int c = j >> 7, k = j & 127;
        W2t[j] = f2bf(W2[k * 64 + c]);
    }
    if (id < n) cnt[id] = 0;
}

// x (f32) -> xb (bf16 packed, row-major [n][128]). One uint4 (8 bf16)/thread.
__global__ __launch_bounds__(256) void cvt_x(const float4* __restrict__ x4,
                                             uint4* __restrict__ xb4, int total) {
    int i = blockIdx.x * 256 + threadIdx.x;
    if (i >= total) return;
    float4 v0 = x4[2 * i], v1 = x4[2 * i + 1];
    uint4 o;
    o.x = (unsigned)f2bf(v0.x) | ((unsigned)f2bf(v0.y) << 16);
    o.y = (unsigned)f2bf(v0.z) | ((unsigned)f2bf(v0.w) << 16);
    o.z = (unsigned)f2bf(v1.x) | ((unsigned)f2bf(v1.y) << 16);
    o.w = (unsigned)f2bf(v1.z) | ((unsigned)f2bf(v1.w) << 16);
    xb4[i] = o;
}

// count + rank in one pass: rank = arrival order within dst bucket.
__global__ void count_k(const int* __restrict__ dst, int* __restrict__ cnt,
                        int* __restrict__ rank, int e) {
    int i = blockIdx.x * blockDim.x + threadIdx.x;
    if (i < e) {
        int r = atomicAdd(&cnt[dst[i]], 1);
        __builtin_nontemporal_store(r, &rank[i]);
    }
}

// Pass 1: per-block inclusive scan of cnt -> incl, block totals -> bsum.
__global__ __launch_bounds__(1024) void scan1_k(const int* __restrict__ cnt,
                                                int* __restrict__ incl,
                                                int* __restrict__ bsum, int n) {
    __shared__ int lds[1024];
    int t = threadIdx.x;
    int i = blockIdx.x * 1024 + t;
    int v = (i < n) ? cnt[i] : 0;
    lds[t] = v;
    __syncthreads();
#pragma unroll
    for (int d = 1; d < 1024; d <<= 1) {
        int u = (t >= d) ? lds[t - d] : 0;
        __syncthreads();
        lds[t] += u;
        __syncthreads();
    }
    if (i < n) incl[i] = lds[t];
    if (t == 1023) bsum[blockIdx.x] = lds[1023];
}

// Pass 2: exclusive scan of the block sums (single wave).
__global__ __launch_bounds__(64) void scan2_k(const int* __restrict__ bsum,
                                              int* __restrict__ bpre, int nb) {
    int t = threadIdx.x;
    int v = (t < nb) ? bsum[t] : 0;
#pragma unroll
    for (int d = 1; d < 64; d <<= 1) {
        int u = __shfl_up(v, d);
        if (t >= d) v += u;
    }
    if (t < nb) bpre[t] = v - bsum[t];   // exclusive
}

// Pass 3: offs (exclusive prefix), dinv, sentinel offs[n].
__global__ __launch_bounds__(1024) void scan3_k(const int* __restrict__ cnt,
                                                const int* __restrict__ incl,
                                                const int* __restrict__ bpre,
                                                int* __restrict__ offs,
                                                float* __restrict__ dinv, int n) {
    int i = blockIdx.x * 1024 + threadIdx.x;
    if (i >= n) return;
    int c = cnt[i];
    int inc = incl[i] + bpre[blockIdx.x];
    offs[i] = inc - c;
    dinv[i] = rsqrtf((float)(c + 1));    // deg includes self loop
    if (i == n - 1) offs[n] = inc;
}

// Scatter packed (src<<16 | bf16(w)) into CSR slots. 4B payload, no atomics.
__global__ void fill_k(const int* __restrict__ src, const int* __restrict__ dst,
                       const int* __restrict__ rank, const int* __restrict__ offs,
                       const float* __restrict__ dinv,
                       unsigned* __restrict__ epk, int e) {
    int i = blockIdx.x * blockDim.x + threadIdx.x;
    if (i >= e) return;
    int s = src[i], d = dst[i];
    float w = dinv[s] * dinv[d];         // in (0,1], sign bit 0 -> bf16 fits 16b
    epk[offs[d] + rank[i]] = ((unsigned)s << 16) | (unsigned)f2bf(w);
}

// MFMA GEMM: Ab(bf16 [n][128]) @ Wt^T (Wt = bf16 [NT*16][128], k-contiguous)
// -> tab (bf16 [n][NT*16]). Block = 64 rows, 4 waves; wave w owns rows
// [16w,16w+16). A-tile staged to LDS as 16B chunks, XOR-swizzled
// (chunk ^= row&7) so frag ds_read_b128 is bank-balanced. K=128 unrolled:
// 4 k-steps x NT mfma_f32_16x16x32_bf16. B-frags straight from L2-resident Wt
// (lane (col,kg) reads 16B of Wt[col] -> 16 full 64B lines per instruction).
// D layout (m89): col = lane&15, row = 4*(lane>>4) + reg.
template<int NT>
__global__ __launch_bounds__(256) void gemm_mfma(const uint4* __restrict__ Ab,
                                                 const uint4* __restrict__ Wt,
                                                 unsigned short* __restrict__ tab,
                                                 int n) {
    __shared__ uint4 As[64 * 16];   // 16 KB
    int t = threadIdx.x;
    int r0 = blockIdx.x * 64;
    int rows = min(64, n - r0);
#pragma unroll
    for (int it = 0; it < 4; ++it) {
        int u = it * 256 + t;
        int row = u >> 4, s = u & 15;
        uint4 v = make_uint4(0u, 0u, 0u, 0u);
        if (row < rows) v = Ab[(size_t)(r0 + row) * 16 + s];
        As[row * 16 + (s ^ (row & 7))] = v;
    }
    __syncthreads();

    int wv = t >> 6, lane = t & 63;
    int arow = lane & 15;            // A-row within stripe / B-col within tile
    int kg = lane >> 4;              // k-group (frags) / row-group (D)
    int lrow = wv * 16 + arow;

    f32x4 acc[NT];
    f32x4 z = {0.f, 0.f, 0.f, 0.f};
#pragma unroll
    for (int j = 0; j < NT; ++j) acc[j] = z;

#pragma unroll
    for (int ks = 0; ks < 4; ++ks) {
        bf16x8 a = __builtin_bit_cast(bf16x8,
                       As[lrow * 16 + ((ks * 4 + kg) ^ (arow & 7))]);
#pragma unroll
        for (int tl = 0; tl < NT; ++tl) {
            bf16x8 b = __builtin_bit_cast(bf16x8,
                           Wt[(size_t)(tl * 16 + arow) * 16 + ks * 4 + kg]);
            acc[tl] = __builtin_amdgcn_mfma_f32_16x16x32_bf16(a, b, acc[tl], 0, 0, 0);
        }
    }

    int grow0 = r0 + wv * 16 + 4 * kg;
#pragma unroll
    for (int r = 0; r < 4; ++r) {
        int grow = grow0 + r;
        if (grow < n) {
            unsigned short* rowp = tab + (size_t)grow * (NT * 16) + arow;
#pragma unroll
            for (int tl = 0; tl < NT; ++tl)
                rowp[tl * 16] = f2bf(acc[tl][r]);
        }
    }
}

// Layer 1 propagation + bias + LayerNorm + ReLU. One wave per node, lane
// holds features {2*lane, 2*lane+1}. 8-deep gather pipeline; edge weight
// unpacked from the payload. Writes h1 as packed bf16 (gemm2 input).
__global__ __launch_bounds__(256) void prop_ln(const unsigned* __restrict__ h0b,
                                               const int* __restrict__ offs,
                                               const unsigned* __restrict__ epk,
                                               const float* __restrict__ dinv,
                                               const float* __restrict__ b1,
                                               const float* __restrict__ gamma,
                                               const float* __restrict__ beta,
                                               unsigned* __restrict__ h1b, int n) {
    int wid = __builtin_amdgcn_readfirstlane((blockIdx.x * blockDim.x + threadIdx.x) >> 6);
    int lane = threadIdx.x & 63;
    if (wid >= n) return;
    float di = dinv[wid];
    unsigned self = h0b[(size_t)wid * 64 + lane];
    float a0 = bfLo(self) * di * di;   // self loop, norm = dinv^2
    float a1 = bfHi(self) * di * di;

    int s0 = offs[wid], s1 = offs[wid + 1];
    if (s0 < s1) {
        int k = s0;
        int sj[8]; float wj[8];
#pragma unroll
        for (int j = 0; j < 8; ++j) {
            int idx = k + j;
            unsigned p = __builtin_nontemporal_load(&epk[min(idx, s1 - 1)]);
            sj[j] = (int)(p >> 16);
            wj[j] = (idx < s1) ? bfLo(p) : 0.f;
        }
        while (k < s1) {
            unsigned g[8];
#pragma unroll
            for (int j = 0; j < 8; ++j) g[j] = h0b[(size_t)sj[j] * 64 + lane];
            k += 8;
            int s2[8]; float w2[8];
#pragma unroll
            for (int j = 0; j < 8; ++j) {
                int idx = k + j;
                unsigned p = __builtin_nontemporal_load(&epk[min(max(idx, s0), s1 - 1)]);
                s2[j] = (int)(p >> 16);
                w2[j] = (idx < s1) ? bfLo(p) : 0.f;
            }
#pragma unroll
            for (int j = 0; j < 8; ++j) {
                a0 = fmaf(bfLo(g[j]), wj[j], a0);
                a1 = fmaf(bfHi(g[j]), wj[j], a1);
            }
#pragma unroll
            for (int j = 0; j < 8; ++j) { sj[j] = s2[j]; wj[j] = w2[j]; }
        }
    }

    a0 += b1[2 * lane];
    a1 += b1[2 * lane + 1];
    // LayerNorm over 128 features spread across the 64-lane wave
    float sum = a0 + a1, sq = a0 * a0 + a1 * a1;
#pragma unroll
    for (int off = 32; off > 0; off >>= 1) {
        sum += __shfl_xor(sum, off);
        sq  += __shfl_xor(sq, off);
    }
    float mu  = sum * (1.f / 128.f);
    float var = fmaxf(sq * (1.f / 128.f) - mu * mu, 0.f);
    float rstd = rsqrtf(var + 1e-6f);
    float y0 = fmaxf((a0 - mu) * rstd * gamma[2 * lane] + beta[2 * lane], 0.f);
    float y1 = fmaxf((a1 - mu) * rstd * gamma[2 * lane + 1] + beta[2 * lane + 1], 0.f);
    unsigned pk = (unsigned)f2bf(y0) | ((unsigned)f2bf(y1) << 16);
    __builtin_nontemporal_store(pk, &h1b[(size_t)wid * 64 + lane]);
}

// Layer 2 propagation + bias. One wave per node; 2 edges per instruction:
// lane = (es = lane>>5) x (u = lane&31: uint chunk of the 64-feature row).
// 8-deep pipeline = 16 edges in flight; final shfl_xor(32) reduce.
__global__ __launch_bounds__(256) void prop_out(const unsigned* __restrict__ h2b,
                                                const int* __restrict__ offs,
                                                const unsigned* __restrict__ epk,
                                                const float* __restrict__ dinv,
                                                const float* __restrict__ b2,
                                                float* __restrict__ out, int n) {
    int wid = __builtin_amdgcn_readfirstlane((blockIdx.x * blockDim.x + threadIdx.x) >> 6);
    int lane = threadIdx.x & 63;
    if (wid >= n) return;
    int es = lane >> 5, u = lane & 31;
    float di = dinv[wid];
    float a0 = 0.f, a1 = 0.f;
    if (es == 0) {
        unsigned self = h2b[(size_t)wid * 32 + u];
        a0 = bfLo(self) * di * di;
        a1 = bfHi(self) * di * di;
    }

    int s0 = offs[wid], s1 = offs[wid + 1];
    if (s0 < s1) {
        int k = s0;
        int sj[8]; float wj[8];
#pragma unroll
        for (int j = 0; j < 8; ++j) {
            int idx = k + 2 * j + es;
            unsigned p = __builtin_nontemporal_load(&epk[min(idx, s1 - 1)]);
            sj[j] = (int)(p >> 16);
            wj[j] = (idx < s1) ? bfLo(p) : 0.f;
        }
        while (k < s1) {
            unsigned g[8];
#pragma unroll
            for (int j = 0; j < 8; ++j) g[j] = h2b[(size_t)sj[j] * 32 + u];
            k += 16;
            int s2[8]; float w2[8];
#pragma unroll
            for (int j = 0; j < 8; ++j) {
                int idx = k + 2 * j + es;
                unsigned p = __builtin_nontemporal_load(&epk[min(max(idx, s0), s1 - 1)]);
                s2[j] = (int)(p >> 16);
                w2[j] = (idx < s1) ? bfLo(p) : 0.f;
            }
#pragma unroll
            for (int j = 0; j < 8; ++j) {
                a0 = fmaf(bfLo(g[j]), wj[j], a0);
                a1 = fmaf(bfHi(g[j]), wj[j], a1);
            }
#pragma unroll
            for (int j = 0; j < 8; ++j) { sj[j] = s2[j]; wj[j] = w2[j]; }
        }
    }

    a0 += __shfl_xor(a0, 32);
    a1 += __shfl_xor(a1, 32);
    if (es == 0) {
        f32x2 o; o.x = a0 + b2[2 * u]; o.y = a1 + b2[2 * u + 1];
        __builtin_nontemporal_store(o, &((f32x2*)out)[(size_t)wid * 32 + u]);
    }
}

extern "C" void kernel_launch(void* const* d_in, const int* in_sizes, int n_in,
                              void* d_out, int out_size, void* d_ws, size_t ws_size,
                              hipStream_t stream) {
    const float* x     = (const float*)d_in[0];
    const int*   ei    = (const int*)d_in[1];
    const float* W1    = (const float*)d_in[2];
    const float* b1    = (const float*)d_in[3];
    const float* gam   = (const float*)d_in[4];
    const float* bet   = (const float*)d_in[5];
    const float* W2    = (const float*)d_in[6];
    const float* b2    = (const float*)d_in[7];
    float* out = (float*)d_out;

    int n = in_sizes[0] / 128;   // 50000  (must stay < 65536 for packed src)
    int e = in_sizes[1] / 2;     // 800000
    const int* src = ei;
    const int* dst = ei + e;

    char* p = (char*)d_ws;
    auto alloc = [&](size_t bytes) {
        void* q = (void*)p;
        p += (bytes + 255) & ~(size_t)255;
        return q;
    };
    int*            cnt   = (int*)alloc((size_t)n * 4);
    int*            offs  = (int*)alloc((size_t)(n + 1) * 4);
    int*            rank  = (int*)alloc((size_t)e * 4);
    float*          dinv  = (float*)alloc((size_t)n * 4);
    unsigned*       epk   = (unsigned*)alloc((size_t)e * 4);
    unsigned*       h0b   = (unsigned*)alloc((size_t)n * 64 * 4);   // bf16 [n][128] (12.8MB)
    char*           h1buf = (char*)alloc((size_t)n * 128 * 4);      // 25.6MB, split below
    unsigned short* W1t   = (unsigned short*)alloc(128 * 128 * 2);
    unsigned short* W2t   = (unsigned short*)alloc(64 * 128 * 2);

    // h1buf: first half = h1b (bf16 [n][128], written by prop_ln, read by gemm2);
    //        second half = xb (bf16 [n][128], written by cvt_x, dead after gemm1).
    unsigned* h1b = (unsigned*)h1buf;
    uint4*    xb  = (uint4*)(h1buf + (size_t)n * 64 * 4);
    // Layer-2 table [n][32] aliases h0b (h0b dead after prop_ln).
    unsigned* h2b = h0b;
    // Scan scratch also aliases h0b (dead before gemm1 writes it).
    int* incl = (int*)h0b;
    int* bsum = incl + n;
    int* bpre = bsum + 64;

    int nb = (n + 1023) / 1024;  // 49 blocks for n=50000

    cvt_wi<<<(n + 255) / 256, 256, 0, stream>>>(W1, W2, W1t, W2t, cnt, n);
    cvt_x<<<(n * 16 + 255) / 256, 256, 0, stream>>>((const float4*)x, xb, n * 16);
    count_k<<<(e + 255) / 256, 256, 0, stream>>>(dst, cnt, rank, e);
    scan1_k<<<nb, 1024, 0, stream>>>(cnt, incl, bsum, n);
    scan2_k<<<1, 64, 0, stream>>>(bsum, bpre, nb);
    scan3_k<<<nb, 1024, 0, stream>>>(cnt, incl, bpre, offs, dinv, n);
    fill_k<<<(e + 255) / 256, 256, 0, stream>>>(src, dst, rank, offs, dinv, epk, e);

    int gb = (n + 63) / 64;      // 782 blocks
    gemm_mfma<8><<<gb, 256, 0, stream>>>(xb, (const uint4*)W1t,
                                         (unsigned short*)h0b, n);
    prop_ln<<<(n + 3) / 4, 256, 0, stream>>>(h0b, offs, epk, dinv, b1, gam, bet, h1b, n);
    gemm_mfma<4><<<gb, 256, 0, stream>>>((const uint4*)h1b, (const uint4*)W2t,
                                         (unsigned short*)h2b, n);
    prop_out<<<(n + 3) / 4, 256, 0, stream>>>(h2b, offs, epk, dinv, b2, out, n);
}